// Round 1
// baseline (522.379 us; speedup 1.0000x reference)
//
#include <hip/hip_runtime.h>
#include <math.h>

#define SEQ 8192
#define HDIM 1024
#define FDIM 128

// ---------------------------------------------------------------------------
// K1: column sums of query (1, SEQ, HDIM) -> qsum[HDIM]  (mean applied later)
// 256 blocks x 256 threads; thread t owns float4-column t (4 floats);
// each block handles 32 rows; atomicAdd partial sums.
// ---------------------------------------------------------------------------
__global__ void qsum_kernel(const float* __restrict__ q, float* __restrict__ qsum) {
    const int col = threadIdx.x;               // 0..255 (float4 column)
    const int rows_per_blk = SEQ / gridDim.x;  // 32
    const int r0 = blockIdx.x * rows_per_blk;
    const float4* q4 = (const float4*)q;
    float4 acc = make_float4(0.f, 0.f, 0.f, 0.f);
    for (int r = 0; r < rows_per_blk; ++r) {
        float4 v = q4[(size_t)(r0 + r) * (HDIM / 4) + col];
        acc.x += v.x; acc.y += v.y; acc.z += v.z; acc.w += v.w;
    }
    atomicAdd(&qsum[col * 4 + 0], acc.x);
    atomicAdd(&qsum[col * 4 + 1], acc.y);
    atomicAdd(&qsum[col * 4 + 2], acc.z);
    atomicAdd(&qsum[col * 4 + 3], acc.w);
}

// ---------------------------------------------------------------------------
// K2: head MLP — temporal MLP, mem = dg + temporal, attention score -> weight.
// One block, 256 threads (k = tid>>7, i = tid&127).
// ---------------------------------------------------------------------------
__global__ void head_kernel(const float* __restrict__ ts, const float* __restrict__ dg,
                            const float* __restrict__ Wt1, const float* __restrict__ bt1,
                            const float* __restrict__ Wt2, const float* __restrict__ bt2,
                            const float* __restrict__ Wa1, const float* __restrict__ ba1,
                            const float* __restrict__ Wa2, const float* __restrict__ ba2,
                            const float* __restrict__ qsum,
                            float* __restrict__ mem_out, float* __restrict__ weight_out) {
    __shared__ float s_mem[2][FDIM];
    __shared__ float s_qm[HDIM];
    __shared__ float s_a1[2][FDIM];
    const int tid = threadIdx.x;
    const int k = tid >> 7, i = tid & 127;

    for (int h = tid; h < HDIM; h += 256) s_qm[h] = qsum[h] * (1.0f / (float)SEQ);

    // temporal MLP: hidden = relu(t*Wt1 + bt1) (32), temporal_i = hidden @ Wt2 + bt2
    {
        const float t = ts[k];
        float acc = bt2[i];
        #pragma unroll
        for (int j = 0; j < 32; ++j) {
            float hj = fmaxf(t * Wt1[j] + bt1[j], 0.0f);
            acc += hj * Wt2[j * FDIM + i];
        }
        s_mem[k][i] = dg[k * FDIM + i] + acc;
    }
    __syncthreads();

    // a1[k][i] = tanh( [mem_k ; qmean] @ Wa1[:,i] + ba1[i] ), Wa1 is (1152,128) row-major
    {
        float acc = ba1[i];
        #pragma unroll 4
        for (int f = 0; f < FDIM; ++f) acc += s_mem[k][f] * Wa1[f * FDIM + i];
        #pragma unroll 4
        for (int h = 0; h < HDIM; ++h) acc += s_qm[h] * Wa1[(FDIM + h) * FDIM + i];
        s_a1[k][i] = tanhf(acc);
    }
    __syncthreads();

    if (tid < 2) {
        float acc = ba2[0];
        for (int j = 0; j < FDIM; ++j) acc += s_a1[tid][j] * Wa2[j];
        weight_out[tid] = 1.0f / (1.0f + expf(-acc));
    }
    mem_out[tid] = s_mem[k][i];
}

// ---------------------------------------------------------------------------
// K3: gw[h] = 0.5 * sum_k weight[k] * ( bg[h] + sum_f mem[k][f]*Wg[f][h] )
// 4 blocks x 256 threads, one h per thread.
// ---------------------------------------------------------------------------
__global__ void gw_kernel(const float* __restrict__ Wg, const float* __restrict__ bg,
                          const float* __restrict__ mem, const float* __restrict__ weight,
                          float* __restrict__ gw) {
    const int h = blockIdx.x * blockDim.x + threadIdx.x;  // 0..1023
    float g0 = bg[h], g1 = g0;
    #pragma unroll 4
    for (int f = 0; f < FDIM; ++f) {
        const float w = Wg[f * HDIM + h];
        g0 += mem[f] * w;
        g1 += mem[FDIM + f] * w;
    }
    gw[h] = 0.5f * (weight[0] * g0 + weight[1] * g1);
}

// ---------------------------------------------------------------------------
// K4: mean_row[s] = dot(key[s, :], gw).  One wave (64 lanes) per row.
// 2048 blocks x 256 threads (4 waves/block).
// ---------------------------------------------------------------------------
__global__ void rowdot_kernel(const float* __restrict__ key, const float* __restrict__ gw,
                              float* __restrict__ mrow) {
    const int lane = threadIdx.x & 63;
    const int wave = threadIdx.x >> 6;
    const int row  = blockIdx.x * 4 + wave;
    const float4* k4 = (const float4*)(key + (size_t)row * HDIM);
    const float4* g4 = (const float4*)gw;
    float acc = 0.f;
    #pragma unroll
    for (int i = 0; i < 4; ++i) {
        const int idx = lane + 64 * i;  // 256 float4 per row
        float4 a = k4[idx];
        float4 b = g4[idx];
        acc += a.x * b.x + a.y * b.y + a.z * b.z + a.w * b.w;
    }
    #pragma unroll
    for (int off = 32; off > 0; off >>= 1) acc += __shfl_down(acc, off);
    if (lane == 0) mrow[row] = acc;
}

// ---------------------------------------------------------------------------
// K5: out[r, c] = mean_row[c] for all r — 256 MB broadcast write, float4.
// ---------------------------------------------------------------------------
__global__ void bcast_kernel(const float* __restrict__ mrow, float4* __restrict__ out) {
    const float4* m4 = (const float4*)mrow;
    const size_t total = (size_t)SEQ * SEQ / 4;  // 16,777,216 float4
    size_t i = (size_t)blockIdx.x * blockDim.x + threadIdx.x;
    const size_t stride = (size_t)gridDim.x * blockDim.x;
    for (; i < total; i += stride) {
        out[i] = m4[i & (SEQ / 4 - 1)];  // row length = 2048 float4
    }
}

extern "C" void kernel_launch(void* const* d_in, const int* in_sizes, int n_in,
                              void* d_out, int out_size, void* d_ws, size_t ws_size,
                              hipStream_t stream) {
    const float* query = (const float*)d_in[0];   // (1, 8192, 1024)
    const float* key   = (const float*)d_in[1];   // (1, 8192, 1024)
    const float* dg    = (const float*)d_in[2];   // (2, 128)
    const float* ts    = (const float*)d_in[3];   // (2,)
    const float* Wt1   = (const float*)d_in[4];   // (1, 32)
    const float* bt1   = (const float*)d_in[5];   // (32,)
    const float* Wt2   = (const float*)d_in[6];   // (32, 128)
    const float* bt2   = (const float*)d_in[7];   // (128,)
    const float* Wa1   = (const float*)d_in[8];   // (1152, 128)
    const float* ba1   = (const float*)d_in[9];   // (128,)
    const float* Wa2   = (const float*)d_in[10];  // (128, 1)
    const float* ba2   = (const float*)d_in[11];  // (1,)
    const float* Wg    = (const float*)d_in[12];  // (128, 1024)
    const float* bg    = (const float*)d_in[13];  // (1024,)

    float* ws     = (float*)d_ws;
    float* qsum   = ws;          // 1024
    float* memv   = ws + 1024;   // 256 (2x128)
    float* weight = ws + 1280;   // 2
    float* gw     = ws + 2048;   // 1024
    float* mrow   = ws + 4096;   // 8192

    hipMemsetAsync(qsum, 0, HDIM * sizeof(float), stream);
    qsum_kernel<<<256, 256, 0, stream>>>(query, qsum);
    head_kernel<<<1, 256, 0, stream>>>(ts, dg, Wt1, bt1, Wt2, bt2, Wa1, ba1, Wa2, ba2,
                                       qsum, memv, weight);
    gw_kernel<<<4, 256, 0, stream>>>(Wg, bg, memv, weight, gw);
    rowdot_kernel<<<SEQ / 4, 256, 0, stream>>>(key, gw, mrow);
    bcast_kernel<<<16384, 256, 0, stream>>>(mrow, (float4*)d_out);
}

// Round 2
// 393.899 us; speedup vs baseline: 1.3262x; 1.3262x over previous
//
#include <hip/hip_runtime.h>
#include <math.h>

#define SEQ 8192
#define HDIM 1024
#define FDIM 128
#define NPART 256   // qsum partial blocks

// ---------------------------------------------------------------------------
// K1: per-block partial column sums of query (SEQ, HDIM) -> part[NPART][HDIM]
// 256 blocks x 256 threads; thread t owns float4-column t; block sums 32 rows.
// No atomics, no memset needed.
// ---------------------------------------------------------------------------
__global__ void qsum_part_kernel(const float* __restrict__ q, float* __restrict__ part) {
    const int col = threadIdx.x;               // float4 column 0..255
    const int rows_per_blk = SEQ / NPART;      // 32
    const int r0 = blockIdx.x * rows_per_blk;
    const float4* q4 = (const float4*)q;
    float4 acc = make_float4(0.f, 0.f, 0.f, 0.f);
    #pragma unroll 8
    for (int r = 0; r < rows_per_blk; ++r) {
        float4 v = q4[(size_t)(r0 + r) * (HDIM / 4) + col];
        acc.x += v.x; acc.y += v.y; acc.z += v.z; acc.w += v.w;
    }
    ((float4*)part)[blockIdx.x * (HDIM / 4) + col] = acc;
}

// ---------------------------------------------------------------------------
// K2 (fused head): reduce qsum partials -> qmean; temporal MLP -> mem;
// attention score -> weight; gw = 0.5*sum_k w_k*(mem_k@Wg + bg).
// One block, 1024 threads (16 waves for latency hiding).
// ---------------------------------------------------------------------------
__global__ void __launch_bounds__(1024)
head_fused_kernel(const float* __restrict__ ts, const float* __restrict__ dg,
                  const float* __restrict__ Wt1, const float* __restrict__ bt1,
                  const float* __restrict__ Wt2, const float* __restrict__ bt2,
                  const float* __restrict__ Wa1, const float* __restrict__ ba1,
                  const float* __restrict__ Wa2, const float* __restrict__ ba2,
                  const float* __restrict__ Wg, const float* __restrict__ bg,
                  const float* __restrict__ part, float* __restrict__ gw) {
    __shared__ float s_qm[HDIM];
    __shared__ float s_mem[2 * FDIM];
    __shared__ float s_part[4][2 * FDIM];
    __shared__ float s_a1[2 * FDIM];
    __shared__ float s_w[2];
    const int tid = threadIdx.x;

    // Phase 0: qmean[h] = sum_b part[b][h] / SEQ  (1 MB coalesced read)
    {
        float acc = 0.f;
        #pragma unroll 8
        for (int b = 0; b < NPART; ++b) acc += part[b * HDIM + tid];
        s_qm[tid] = acc * (1.0f / (float)SEQ);
    }

    // Phase 1: temporal MLP (threads 0..255): mem[k][i]
    if (tid < 2 * FDIM) {
        const int k = tid >> 7, i = tid & 127;
        const float t = ts[k];
        float acc = bt2[i];
        #pragma unroll
        for (int j = 0; j < 32; ++j) {
            float hj = fmaxf(t * Wt1[j] + bt1[j], 0.0f);
            acc += hj * Wt2[j * FDIM + i];
        }
        s_mem[tid] = dg[tid] + acc;
    }
    __syncthreads();

    // Phase 2: a1[k][i] = tanh([mem_k ; qmean] @ Wa1[:,i] + ba1[i])
    // 4-way split of the 1152-dim reduction: p = tid>>8, output o = tid&255.
    {
        const int p = tid >> 8;           // 0..3
        const int o = tid & 255;          // k*128 + i
        const int k = o >> 7, i = o & 127;
        const int e0 = p * 288, e1 = e0 + 288;
        float acc = 0.f;
        for (int e = e0; e < e1; ++e) {
            const float x = (e < FDIM) ? s_mem[k * FDIM + e] : s_qm[e - FDIM];
            acc += x * Wa1[e * FDIM + i];
        }
        s_part[p][o] = acc;
    }
    __syncthreads();
    if (tid < 2 * FDIM) {
        float acc = ba1[tid & 127] + s_part[0][tid] + s_part[1][tid] + s_part[2][tid] + s_part[3][tid];
        s_a1[tid] = tanhf(acc);
    }
    __syncthreads();

    // Phase 3: weight[k] = sigmoid(a1_k @ Wa2 + ba2)
    if (tid < 2) {
        float acc = ba2[0];
        for (int j = 0; j < FDIM; ++j) acc += s_a1[tid * FDIM + j] * Wa2[j];
        s_w[tid] = 1.0f / (1.0f + expf(-acc));
    }
    __syncthreads();

    // Phase 4: gw[h] = 0.5*(w0*(bg[h]+mem0@Wg[:,h]) + w1*(bg[h]+mem1@Wg[:,h]))
    {
        const int h = tid;
        float g0 = bg[h], g1 = g0;
        #pragma unroll 8
        for (int f = 0; f < FDIM; ++f) {
            const float w = Wg[f * HDIM + h];
            g0 += s_mem[f] * w;
            g1 += s_mem[FDIM + f] * w;
        }
        gw[h] = 0.5f * (s_w[0] * g0 + s_w[1] * g1);
    }
}

// ---------------------------------------------------------------------------
// K3: mean_row[s] = dot(key[s, :], gw). One wave per row, 4 waves/block.
// ---------------------------------------------------------------------------
__global__ void rowdot_kernel(const float* __restrict__ key, const float* __restrict__ gw,
                              float* __restrict__ mrow) {
    const int lane = threadIdx.x & 63;
    const int wave = threadIdx.x >> 6;
    const int row  = blockIdx.x * 4 + wave;
    const float4* k4 = (const float4*)(key + (size_t)row * HDIM);
    const float4* g4 = (const float4*)gw;
    float acc = 0.f;
    #pragma unroll
    for (int i = 0; i < 4; ++i) {
        const int idx = lane + 64 * i;
        float4 a = k4[idx];
        float4 b = g4[idx];
        acc += a.x * b.x + a.y * b.y + a.z * b.z + a.w * b.w;
    }
    #pragma unroll
    for (int off = 32; off > 0; off >>= 1) acc += __shfl_down(acc, off);
    if (lane == 0) mrow[row] = acc;
}

// ---------------------------------------------------------------------------
// K4: out[r, c] = mean_row[c] — 268 MB broadcast write.
// Grid stride (16384*256 = 4.19M) is a multiple of row length (2048 float4),
// so each thread's mrow float4 is invariant: load once, store 4x.
// ---------------------------------------------------------------------------
__global__ void bcast_kernel(const float* __restrict__ mrow, float4* __restrict__ out) {
    const size_t total = (size_t)SEQ * SEQ / 4;              // 16,777,216 float4
    const size_t i0 = (size_t)blockIdx.x * blockDim.x + threadIdx.x;
    const size_t stride = (size_t)gridDim.x * blockDim.x;    // 4,194,304
    const float4 v = ((const float4*)mrow)[i0 & (SEQ / 4 - 1)];
    for (size_t i = i0; i < total; i += stride) out[i] = v;
}

extern "C" void kernel_launch(void* const* d_in, const int* in_sizes, int n_in,
                              void* d_out, int out_size, void* d_ws, size_t ws_size,
                              hipStream_t stream) {
    const float* query = (const float*)d_in[0];
    const float* key   = (const float*)d_in[1];
    const float* dg    = (const float*)d_in[2];
    const float* ts    = (const float*)d_in[3];
    const float* Wt1   = (const float*)d_in[4];
    const float* bt1   = (const float*)d_in[5];
    const float* Wt2   = (const float*)d_in[6];
    const float* bt2   = (const float*)d_in[7];
    const float* Wa1   = (const float*)d_in[8];
    const float* ba1   = (const float*)d_in[9];
    const float* Wa2   = (const float*)d_in[10];
    const float* ba2   = (const float*)d_in[11];
    const float* Wg    = (const float*)d_in[12];
    const float* bg    = (const float*)d_in[13];

    float* ws   = (float*)d_ws;
    float* part = ws;                     // 256*1024 = 262144 floats (1 MB)
    float* gw   = ws + NPART * HDIM;      // 1024
    float* mrow = gw + HDIM;              // 8192

    qsum_part_kernel<<<NPART, 256, 0, stream>>>(query, part);
    head_fused_kernel<<<1, 1024, 0, stream>>>(ts, dg, Wt1, bt1, Wt2, bt2, Wa1, ba1,
                                              Wa2, ba2, Wg, bg, part, gw);
    rowdot_kernel<<<SEQ / 4, 256, 0, stream>>>(key, gw, mrow);
    bcast_kernel<<<16384, 256, 0, stream>>>(mrow, (float4*)d_out);
}